// Round 2
// baseline (189.333 us; speedup 1.0000x reference)
//
#include <hip/hip_runtime.h>
#include <hip/hip_bf16.h>
#include <math.h>

// ---------------------------------------------------------------------------
// Problem constants (from setup_inputs)
#define NPIX   589824      // 768*768
#define NEIK   100000
#define NSDF   100000
#define PP     50000
#define CC     4
#define SPTS   8192        // points per cloud
// fused k_sums region block counts (256 thr each)
#define B_PIX  576         // 576*256   = 147456 threads, 4 pixels each = NPIX
#define B_EIK  98          // 98*256    = 25088 thr, 4 pts each, guard at 25000
#define B_SDF  98
#define B_CON  196         // 196*256   = 50176 thr, 1 point each, guard at 50000
#define B_SUMS (B_PIX + B_EIK + B_SDF + B_CON)   // 968
#define B_FIN  576         // depth pass 2: 576*256*4 == NPIX exactly
// workspace layout (32-bit words):
//  [0]  mask_sum        [1] normal_err_sum  [2] den   [3] num
//  [4]  bce_sum         [5] eik_sum         [6] sdf_sum
//  [7]  con_sum         [8] vis_total       [9] depth_abs_sum
//  [32] finish counter (uint)
//  [64 .. 64+2*SPTS)  chamfer per-source min (uint-encoded positive float)
#define WS_MIN_OFF 64

__device__ __forceinline__ float nan0(float x) { return isfinite(x) ? x : 0.0f; }

__device__ __forceinline__ float waveReduce(float v) {
    v += __shfl_down(v, 32); v += __shfl_down(v, 16); v += __shfl_down(v, 8);
    v += __shfl_down(v, 4);  v += __shfl_down(v, 2);  v += __shfl_down(v, 1);
    return v;
}

// valid on thread 0 only; block must be 256 threads (4 waves)
__device__ __forceinline__ float blockReduce(float v, float* sbuf) {
    v = waveReduce(v);
    int lane = threadIdx.x & 63, w = threadIdx.x >> 6;
    __syncthreads();                  // protect sbuf across back-to-back calls
    if (lane == 0) sbuf[w] = v;
    __syncthreads();
    float r = 0.0f;
    if (threadIdx.x == 0) r = sbuf[0] + sbuf[1] + sbuf[2] + sbuf[3];
    return r;
}

union F12 { float4 v[3]; float f[12]; };

// ---------------------------------------------------------------------------
__global__ __launch_bounds__(256) void k_init(unsigned int* __restrict__ wsu) {
    int i = blockIdx.x * 256 + threadIdx.x;      // grid 64*256 = 16384
    if (i < 64) wsu[i] = 0u;                     // scalars (0.0f) + counters
    wsu[WS_MIN_OFF + i] = 0x7f800000u;           // +inf bit pattern, 16384 entries
}

// ---------------------------------------------------------------------------
__global__ __launch_bounds__(256) void k_sums(
    const float* __restrict__ normal_pred, const float* __restrict__ normal_gt,
    const float* __restrict__ depth_pred,  const float* __restrict__ depth_gt,
    const float* __restrict__ mask,        const float* __restrict__ comp_mask,
    const float* __restrict__ gradients,   const float* __restrict__ sdf,
    const float* __restrict__ nwa,         const float* __restrict__ vm,
    const float* __restrict__ wts,         float* __restrict__ ws)
{
    __shared__ float sbuf[4];
    int b = blockIdx.x;
    int t = threadIdx.x;
    if (b < B_PIX) {
        int g = b * 256 + t;                     // pixel group, 4 pixels
        float4 m4 = ((const float4*)mask)[g];
        float4 c4 = ((const float4*)comp_mask)[g];
        float4 dg4 = ((const float4*)depth_gt)[g];
        float4 dp4 = ((const float4*)depth_pred)[g];
        F12 np, ng;
        np.v[0] = ((const float4*)normal_pred)[3*g];
        np.v[1] = ((const float4*)normal_pred)[3*g+1];
        np.v[2] = ((const float4*)normal_pred)[3*g+2];
        ng.v[0] = ((const float4*)normal_gt)[3*g];
        ng.v[1] = ((const float4*)normal_gt)[3*g+1];
        ng.v[2] = ((const float4*)normal_gt)[3*g+2];
        float mm[4] = { m4.x, m4.y, m4.z, m4.w };
        float cc[4] = { c4.x, c4.y, c4.z, c4.w };
        float gg[4] = { dg4.x, dg4.y, dg4.z, dg4.w };
        float pp[4] = { dp4.x, dp4.y, dp4.z, dp4.w };
        float s_mask = 0, s_nerr = 0, s_den = 0, s_num = 0, s_bce = 0;
#pragma unroll
        for (int k = 0; k < 4; ++k) {
            float m = mm[k] > 0.5f ? 1.0f : 0.0f;
            s_mask += m;
            float e0 = nan0(np.f[3*k])   - nan0(ng.f[3*k]);
            float e1 = nan0(np.f[3*k+1]) - nan0(ng.f[3*k+1]);
            float e2 = nan0(np.f[3*k+2]) - nan0(ng.f[3*k+2]);
            s_nerr += m * (e0*e0 + e1*e1 + e2*e2);
            float vg = (m == 1.0f) ? nan0(gg[k]) : 0.0f;
            float vp = (m == 1.0f) ? nan0(pp[k]) : 0.0f;
            s_den += vg * vg;
            s_num += vg * vp;
            float c = cc[k];
            c = fminf(fmaxf(c, 0.0f), 1.0f);     // clip; +inf->1, -inf->0
            if (isnan(c)) c = 0.5f;              // nan->0.5
            c = fminf(fmaxf(c, 1e-5f), 1.0f - 1e-5f);
            s_bce -= m * __logf(c) + (1.0f - m) * __logf(1.0f - c);
        }
        float r;
        r = blockReduce(s_mask, sbuf); if (t == 0) atomicAdd(&ws[0], r);
        r = blockReduce(s_nerr, sbuf); if (t == 0) atomicAdd(&ws[1], r);
        r = blockReduce(s_den,  sbuf); if (t == 0) atomicAdd(&ws[2], r);
        r = blockReduce(s_num,  sbuf); if (t == 0) atomicAdd(&ws[3], r);
        r = blockReduce(s_bce,  sbuf); if (t == 0) atomicAdd(&ws[4], r);
    } else if (b < B_PIX + B_EIK) {
        int i = (b - B_PIX) * 256 + t;           // group of 4 points
        float acc = 0;
        if (i * 4 < NEIK) {
            F12 gr;
            gr.v[0] = ((const float4*)gradients)[3*i];
            gr.v[1] = ((const float4*)gradients)[3*i+1];
            gr.v[2] = ((const float4*)gradients)[3*i+2];
#pragma unroll
            for (int k = 0; k < 4; ++k) {
                float g0 = gr.f[3*k], g1 = gr.f[3*k+1], g2 = gr.f[3*k+2];
                float n = sqrtf(g0*g0 + g1*g1 + g2*g2) - 1.0f;
                acc += n * n;
            }
        }
        float r = blockReduce(acc, sbuf); if (t == 0) atomicAdd(&ws[5], r);
    } else if (b < B_PIX + B_EIK + B_SDF) {
        int i = (b - B_PIX - B_EIK) * 256 + t;   // group of 4
        float acc = 0;
        if (i * 4 < NSDF) {
            float4 s4 = ((const float4*)sdf)[i];
            acc = fabsf(s4.x) + fabsf(s4.y) + fabsf(s4.z) + fabsf(s4.w);
        }
        float r = blockReduce(acc, sbuf); if (t == 0) atomicAdd(&ws[6], r);
    } else {
        int p = (b - B_PIX - B_EIK - B_SDF) * 256 + t;   // one point, 3 cam pairs
        float s_con = 0, s_vis = 0;
        if (p < PP) {
            F12 a;
            a.v[0] = ((const float4*)nwa)[3*p];
            a.v[1] = ((const float4*)nwa)[3*p+1];
            a.v[2] = ((const float4*)nwa)[3*p+2];
            float4 v4 = ((const float4*)vm)[p];
            float vv[4] = { v4.x, v4.y, v4.z, v4.w };
            float w = wts[p];
#pragma unroll
            for (int pr = 0; pr < 3; ++pr) {
                float d0 = a.f[3*pr]   - a.f[3*pr+3];
                float d1 = a.f[3*pr+1] - a.f[3*pr+4];
                float d2 = a.f[3*pr+2] - a.f[3*pr+5];
                float mse = d0*d0 + d1*d1 + d2*d2;
                float vis = vv[pr] * vv[pr+1];
                s_vis += vis;
                s_con += mse * vis * w;
            }
        }
        float r;
        r = blockReduce(s_con, sbuf); if (t == 0) atomicAdd(&ws[7], r);
        r = blockReduce(s_vis, sbuf); if (t == 0) atomicAdd(&ws[8], r);
    }
}

// ---------------------------------------------------------------------------
// Chamfer: 512 blocks = 2 dirs x 8 src-chunks(1024) x 32 dst-chunks(256).
// rank value r = 0.5*|y|^2 - x.y  (3 FMA + 1 min per pair); final
// d2/2 = min_r + 0.5*|x|^2 folded in before the atomicMin.
__global__ __launch_bounds__(256) void k_chamfer(
    const float* __restrict__ X, const float* __restrict__ Y,
    unsigned int* __restrict__ minarr)
{
    int b   = blockIdx.x;
    int dir = b >> 8;            // 0: X->Y, 1: Y->X
    int r   = b & 255;
    int sc  = r >> 5;            // 0..7
    int dc  = r & 31;            // 0..31
    const float* src = dir ? Y : X;
    const float* dst = dir ? X : Y;
    __shared__ float4 ybuf[256];
    int t = threadIdx.x;
    {
        int d = dc * 256 + t;
        float y0 = dst[3*d], y1 = dst[3*d+1], y2 = dst[3*d+2];
        ybuf[t] = make_float4(y0, y1, y2, 0.5f * (y0*y0 + y1*y1 + y2*y2));
    }
    float nx0[4], nx1[4], nx2[4], hx2[4], mn[4];
#pragma unroll
    for (int j = 0; j < 4; ++j) {
        int s = sc * 1024 + t + j * 256;
        float x0 = src[3*s], x1 = src[3*s+1], x2 = src[3*s+2];
        nx0[j] = -x0; nx1[j] = -x1; nx2[j] = -x2;
        hx2[j] = 0.5f * (x0*x0 + x1*x1 + x2*x2);
        mn[j]  = 1e30f;
    }
    __syncthreads();
#pragma unroll 4
    for (int dd = 0; dd < 256; ++dd) {
        float4 y = ybuf[dd];       // uniform address -> LDS broadcast, no conflicts
#pragma unroll
        for (int j = 0; j < 4; ++j) {
            float rr = fmaf(nx0[j], y.x, y.w);
            rr = fmaf(nx1[j], y.y, rr);
            rr = fmaf(nx2[j], y.z, rr);
            mn[j] = fminf(mn[j], rr);
        }
    }
#pragma unroll
    for (int j = 0; j < 4; ++j) {
        int s = sc * 1024 + t + j * 256;
        float v = mn[j] + hx2[j];                 // = d2_min / 2, >= 0
        atomicMin(&minarr[dir * SPTS + s], __float_as_uint(v));
    }
}

// ---------------------------------------------------------------------------
// depth pass 2 + last-block finalize
__global__ __launch_bounds__(256) void k_final(
    const float* __restrict__ depth_pred, const float* __restrict__ depth_gt,
    const float* __restrict__ mask, float* __restrict__ ws,
    unsigned int* __restrict__ wsu, const unsigned int* __restrict__ minarr,
    float* __restrict__ out)
{
    __shared__ float sbuf[4];
    __shared__ int amlast;
    // den/num written by k_sums (previous kernel on this stream) -> visible
    float den = ws[2], num = ws[3];
    float scale = num / den;
    if (!isfinite(scale)) scale = 1.0f;          // nan_to_num(nan=1, +-inf=1)
    int g = blockIdx.x * 256 + threadIdx.x;      // 4 pixels per thread
    float4 m4  = ((const float4*)mask)[g];
    float4 dg4 = ((const float4*)depth_gt)[g];
    float4 dp4 = ((const float4*)depth_pred)[g];
    float mm[4] = { m4.x, m4.y, m4.z, m4.w };
    float gg[4] = { dg4.x, dg4.y, dg4.z, dg4.w };
    float pp[4] = { dp4.x, dp4.y, dp4.z, dp4.w };
    float acc = 0;
#pragma unroll
    for (int k = 0; k < 4; ++k) {
        float m  = mm[k] > 0.5f ? 1.0f : 0.0f;
        float vg = (m == 1.0f) ? nan0(gg[k]) : 0.0f;
        float vp = (m == 1.0f) ? nan0(pp[k]) : 0.0f;
        acc += fabsf(vg * scale - vp);
    }
    float tot = blockReduce(acc, sbuf);
    if (threadIdx.x == 0) {
        atomicAdd(&ws[9], tot);
        __threadfence();
        unsigned int c = atomicAdd(&wsu[32], 1u);
        amlast = (c == (unsigned int)(B_FIN - 1));
    }
    __syncthreads();
    if (!amlast) return;

    // ---- last block: chamfer finalize + total loss ----
    float pcacc = 0;
    for (int i = threadIdx.x; i < 2 * SPTS; i += 256) {
        float v = __uint_as_float(minarr[i]);    // d2/2
        pcacc += sqrtf(fmaxf(2.0f * v, 0.0f));
    }
    float pcsum = blockReduce(pcacc, sbuf);
    if (threadIdx.x == 0) {
        float mask_sum = atomicAdd(&ws[0], 0.0f) + 1e-5f;
        float normal_loss = atomicAdd(&ws[1], 0.0f) / mask_sum;
        float den_  = atomicAdd(&ws[2], 0.0f);
        float dabs  = atomicAdd(&ws[9], 0.0f);
        float depth_loss = dabs / (mask_sum + 1e-8f);
        if (den_ < 1e-10f) depth_loss = 0.0f;
        depth_loss = nan0(depth_loss);
        float pc_loss  = pcsum / (float)SPTS;    // both dirs share the /8192
        float bce      = atomicAdd(&ws[4], 0.0f) / (float)NPIX;
        float eik      = atomicAdd(&ws[5], 0.0f) / (float)NEIK;
        float sdf_loss = atomicAdd(&ws[6], 0.0f) / (float)NSDF;
        float consum   = atomicAdd(&ws[7], 0.0f);
        float vtot     = atomicAdd(&ws[8], 0.0f);
        float con      = vtot > 0.0f ? consum / vtot : 0.0f;
        out[0] = normal_loss + depth_loss + pc_loss + bce + eik + sdf_loss + con;
    }
}

// ---------------------------------------------------------------------------
extern "C" void kernel_launch(void* const* d_in, const int* in_sizes, int n_in,
                              void* d_out, int out_size, void* d_ws, size_t ws_size,
                              hipStream_t stream) {
    const float* normal_pred = (const float*)d_in[0];
    const float* normal_gt   = (const float*)d_in[1];
    const float* depth_pred  = (const float*)d_in[2];
    const float* depth_gt    = (const float*)d_in[3];
    const float* X           = (const float*)d_in[4];
    const float* Y           = (const float*)d_in[5];
    const float* mask        = (const float*)d_in[6];
    const float* comp_mask   = (const float*)d_in[7];
    const float* gradients   = (const float*)d_in[8];
    const float* sdf         = (const float*)d_in[9];
    const float* nwa         = (const float*)d_in[10];
    const float* vm          = (const float*)d_in[11];
    const float* wts         = (const float*)d_in[12];
    float*        ws  = (float*)d_ws;
    unsigned int* wsu = (unsigned int*)d_ws;
    unsigned int* minarr = wsu + WS_MIN_OFF;
    float* out = (float*)d_out;

    k_init<<<dim3(64), dim3(256), 0, stream>>>(wsu);
    k_sums<<<dim3(B_SUMS), dim3(256), 0, stream>>>(
        normal_pred, normal_gt, depth_pred, depth_gt, mask, comp_mask,
        gradients, sdf, nwa, vm, wts, ws);
    k_chamfer<<<dim3(512), dim3(256), 0, stream>>>(X, Y, minarr);
    k_final<<<dim3(B_FIN), dim3(256), 0, stream>>>(
        depth_pred, depth_gt, mask, ws, wsu, minarr, out);
}

// Round 3
// 125.225 us; speedup vs baseline: 1.5119x; 1.5119x over previous
//
#include <hip/hip_runtime.h>
#include <hip/hip_bf16.h>
#include <math.h>

// ---------------------------------------------------------------------------
// Problem constants (from setup_inputs)
#define NPIX   589824      // 768*768
#define NEIK   100000
#define NSDF   100000
#define PP     50000
#define CC     4
#define SPTS   8192        // points per cloud
// fused k_sums region block counts (256 thr each)
#define B_PIX  576         // 576*256   = 147456 threads, 4 pixels each = NPIX
#define B_EIK  98          // 98*256*4  = 100352, guard at 25000 groups
#define B_SDF  98
#define B_CON  196         // 196*256   = 50176 threads, 1 point each, guard 50000
#define B_SUMS (B_PIX + B_EIK + B_SDF + B_CON)   // 968
#define B_DEP  576         // depth pass 2: 576*256*4 == NPIX exactly
// ---------------------------------------------------------------------------
// workspace layout (32-bit words). Anti-contention: each quantity q (0..9)
// owns its OWN 8 slots, each slot in its OWN 64B cache line:
//   slot word index = q*128 + (blockIdx&7)*16
// quantities: 0 mask_sum, 1 normal_err, 2 den, 3 num, 4 bce, 5 eik, 6 sdf,
//             7 con, 8 vis, 9 depth_abs
#define NQ        10
#define QSTRIDE   128
#define SLOT(q,b) ((q)*QSTRIDE + ((b)&7)*16)
#define OFF_MIN   (NQ*QSTRIDE)            // 1280; chamfer minarr, 16384 words
#define WS_WORDS  (OFF_MIN + 2*SPTS)      // 17664 words = 70.7 KB

__device__ __forceinline__ float nan0(float x) { return isfinite(x) ? x : 0.0f; }

__device__ __forceinline__ float waveReduce(float v) {
    v += __shfl_down(v, 32); v += __shfl_down(v, 16); v += __shfl_down(v, 8);
    v += __shfl_down(v, 4);  v += __shfl_down(v, 2);  v += __shfl_down(v, 1);
    return v;
}

// valid on thread 0 only; block must be 256 threads (4 waves)
__device__ __forceinline__ float blockReduce(float v, float* sbuf) {
    v = waveReduce(v);
    int lane = threadIdx.x & 63, w = threadIdx.x >> 6;
    __syncthreads();                  // protect sbuf across back-to-back calls
    if (lane == 0) sbuf[w] = v;
    __syncthreads();
    float r = 0.0f;
    if (threadIdx.x == 0) r = sbuf[0] + sbuf[1] + sbuf[2] + sbuf[3];
    return r;
}

union F12 { float4 v[3]; float f[12]; };

// ---------------------------------------------------------------------------
__global__ __launch_bounds__(256) void k_init(unsigned int* __restrict__ wsu) {
    int i = blockIdx.x * 256 + threadIdx.x;      // grid 69*256 = 17664 == WS_WORDS
    wsu[i] = (i < OFF_MIN) ? 0u : 0x7f800000u;   // accum slots = 0.0f, mins = +inf
}

// ---------------------------------------------------------------------------
__global__ __launch_bounds__(256) void k_sums(
    const float* __restrict__ normal_pred, const float* __restrict__ normal_gt,
    const float* __restrict__ depth_pred,  const float* __restrict__ depth_gt,
    const float* __restrict__ mask,        const float* __restrict__ comp_mask,
    const float* __restrict__ gradients,   const float* __restrict__ sdf,
    const float* __restrict__ nwa,         const float* __restrict__ vm,
    const float* __restrict__ wts,         float* __restrict__ ws)
{
    __shared__ float sbuf[4];
    int b = blockIdx.x;
    int t = threadIdx.x;
    if (b < B_PIX) {
        int g = b * 256 + t;                     // pixel group, 4 pixels
        float4 m4 = ((const float4*)mask)[g];
        float4 c4 = ((const float4*)comp_mask)[g];
        float4 dg4 = ((const float4*)depth_gt)[g];
        float4 dp4 = ((const float4*)depth_pred)[g];
        F12 np, ng;
        np.v[0] = ((const float4*)normal_pred)[3*g];
        np.v[1] = ((const float4*)normal_pred)[3*g+1];
        np.v[2] = ((const float4*)normal_pred)[3*g+2];
        ng.v[0] = ((const float4*)normal_gt)[3*g];
        ng.v[1] = ((const float4*)normal_gt)[3*g+1];
        ng.v[2] = ((const float4*)normal_gt)[3*g+2];
        float mm[4] = { m4.x, m4.y, m4.z, m4.w };
        float cc[4] = { c4.x, c4.y, c4.z, c4.w };
        float gg[4] = { dg4.x, dg4.y, dg4.z, dg4.w };
        float pp[4] = { dp4.x, dp4.y, dp4.z, dp4.w };
        float s_mask = 0, s_nerr = 0, s_den = 0, s_num = 0, s_bce = 0;
#pragma unroll
        for (int k = 0; k < 4; ++k) {
            float m = mm[k] > 0.5f ? 1.0f : 0.0f;
            s_mask += m;
            float e0 = nan0(np.f[3*k])   - nan0(ng.f[3*k]);
            float e1 = nan0(np.f[3*k+1]) - nan0(ng.f[3*k+1]);
            float e2 = nan0(np.f[3*k+2]) - nan0(ng.f[3*k+2]);
            s_nerr += m * (e0*e0 + e1*e1 + e2*e2);
            float vg = (m == 1.0f) ? nan0(gg[k]) : 0.0f;
            float vp = (m == 1.0f) ? nan0(pp[k]) : 0.0f;
            s_den += vg * vg;
            s_num += vg * vp;
            float c = cc[k];
            c = fminf(fmaxf(c, 0.0f), 1.0f);     // clip; +inf->1, -inf->0
            if (isnan(c)) c = 0.5f;              // nan->0.5
            c = fminf(fmaxf(c, 1e-5f), 1.0f - 1e-5f);
            s_bce -= m * __logf(c) + (1.0f - m) * __logf(1.0f - c);
        }
        float r;
        r = blockReduce(s_mask, sbuf); if (t == 0) atomicAdd(&ws[SLOT(0,b)], r);
        r = blockReduce(s_nerr, sbuf); if (t == 0) atomicAdd(&ws[SLOT(1,b)], r);
        r = blockReduce(s_den,  sbuf); if (t == 0) atomicAdd(&ws[SLOT(2,b)], r);
        r = blockReduce(s_num,  sbuf); if (t == 0) atomicAdd(&ws[SLOT(3,b)], r);
        r = blockReduce(s_bce,  sbuf); if (t == 0) atomicAdd(&ws[SLOT(4,b)], r);
    } else if (b < B_PIX + B_EIK) {
        int i = (b - B_PIX) * 256 + t;           // group of 4 points
        float acc = 0;
        if (i < NEIK / 4) {
            F12 gr;
            gr.v[0] = ((const float4*)gradients)[3*i];
            gr.v[1] = ((const float4*)gradients)[3*i+1];
            gr.v[2] = ((const float4*)gradients)[3*i+2];
#pragma unroll
            for (int k = 0; k < 4; ++k) {
                float g0 = gr.f[3*k], g1 = gr.f[3*k+1], g2 = gr.f[3*k+2];
                float n = sqrtf(g0*g0 + g1*g1 + g2*g2) - 1.0f;
                acc += n * n;
            }
        }
        float r = blockReduce(acc, sbuf); if (t == 0) atomicAdd(&ws[SLOT(5,b)], r);
    } else if (b < B_PIX + B_EIK + B_SDF) {
        int i = (b - B_PIX - B_EIK) * 256 + t;   // group of 4
        float acc = 0;
        if (i < NSDF / 4) {
            float4 s4 = ((const float4*)sdf)[i];
            acc = fabsf(s4.x) + fabsf(s4.y) + fabsf(s4.z) + fabsf(s4.w);
        }
        float r = blockReduce(acc, sbuf); if (t == 0) atomicAdd(&ws[SLOT(6,b)], r);
    } else {
        int p = (b - B_PIX - B_EIK - B_SDF) * 256 + t;   // one point, 3 cam pairs
        float s_con = 0, s_vis = 0;
        if (p < PP) {
            F12 a;
            a.v[0] = ((const float4*)nwa)[3*p];
            a.v[1] = ((const float4*)nwa)[3*p+1];
            a.v[2] = ((const float4*)nwa)[3*p+2];
            float4 v4 = ((const float4*)vm)[p];
            float vv[4] = { v4.x, v4.y, v4.z, v4.w };
            float w = wts[p];
#pragma unroll
            for (int pr = 0; pr < 3; ++pr) {
                float d0 = a.f[3*pr]   - a.f[3*pr+3];
                float d1 = a.f[3*pr+1] - a.f[3*pr+4];
                float d2 = a.f[3*pr+2] - a.f[3*pr+5];
                float mse = d0*d0 + d1*d1 + d2*d2;
                float vis = vv[pr] * vv[pr+1];
                s_vis += vis;
                s_con += mse * vis * w;
            }
        }
        float r;
        r = blockReduce(s_con, sbuf); if (t == 0) atomicAdd(&ws[SLOT(7,b)], r);
        r = blockReduce(s_vis, sbuf); if (t == 0) atomicAdd(&ws[SLOT(8,b)], r);
    }
}

// ---------------------------------------------------------------------------
// Chamfer: 512 blocks = 2 dirs x 8 src-chunks(1024) x 32 dst-chunks(256).
// rank value r = 0.5*|y|^2 - x.y  (3 FMA + 1 min per pair); final
// d2/2 = min_r + 0.5*|x|^2 folded in before the atomicMin. Mins are spread
// over 64KB of distinct addresses -> no atomic contention.
__global__ __launch_bounds__(256) void k_chamfer(
    const float* __restrict__ X, const float* __restrict__ Y,
    unsigned int* __restrict__ minarr)
{
    int b   = blockIdx.x;
    int dir = b >> 8;            // 0: X->Y, 1: Y->X
    int r   = b & 255;
    int sc  = r >> 5;            // 0..7
    int dc  = r & 31;            // 0..31
    const float* src = dir ? Y : X;
    const float* dst = dir ? X : Y;
    __shared__ float4 ybuf[256];
    int t = threadIdx.x;
    {
        int d = dc * 256 + t;
        float y0 = dst[3*d], y1 = dst[3*d+1], y2 = dst[3*d+2];
        ybuf[t] = make_float4(y0, y1, y2, 0.5f * (y0*y0 + y1*y1 + y2*y2));
    }
    float nx0[4], nx1[4], nx2[4], hx2[4], mn[4];
#pragma unroll
    for (int j = 0; j < 4; ++j) {
        int s = sc * 1024 + t + j * 256;
        float x0 = src[3*s], x1 = src[3*s+1], x2 = src[3*s+2];
        nx0[j] = -x0; nx1[j] = -x1; nx2[j] = -x2;
        hx2[j] = 0.5f * (x0*x0 + x1*x1 + x2*x2);
        mn[j]  = 1e30f;
    }
    __syncthreads();
#pragma unroll 4
    for (int dd = 0; dd < 256; ++dd) {
        float4 y = ybuf[dd];       // uniform address -> LDS broadcast, no conflicts
#pragma unroll
        for (int j = 0; j < 4; ++j) {
            float rr = fmaf(nx0[j], y.x, y.w);
            rr = fmaf(nx1[j], y.y, rr);
            rr = fmaf(nx2[j], y.z, rr);
            mn[j] = fminf(mn[j], rr);
        }
    }
#pragma unroll
    for (int j = 0; j < 4; ++j) {
        int s = sc * 1024 + t + j * 256;
        float v = mn[j] + hx2[j];                 // = d2_min / 2, >= 0
        atomicMin(&minarr[dir * SPTS + s], __float_as_uint(v));
    }
}

// ---------------------------------------------------------------------------
// depth pass 2: reads den/num slots (written by k_sums, prior kernel on the
// stream -> visible), computes scale locally, accumulates |vg*scale - vp|.
__global__ __launch_bounds__(256) void k_depth(
    const float* __restrict__ depth_pred, const float* __restrict__ depth_gt,
    const float* __restrict__ mask, float* __restrict__ ws)
{
    __shared__ float sbuf[4];
    float den = 0, num = 0;
#pragma unroll
    for (int s = 0; s < 8; ++s) {
        den += ws[2*QSTRIDE + s*16];
        num += ws[3*QSTRIDE + s*16];
    }
    float scale = num / den;
    if (!isfinite(scale)) scale = 1.0f;          // nan_to_num(nan=1, +-inf=1)
    int g = blockIdx.x * 256 + threadIdx.x;      // 4 pixels per thread
    float4 m4  = ((const float4*)mask)[g];
    float4 dg4 = ((const float4*)depth_gt)[g];
    float4 dp4 = ((const float4*)depth_pred)[g];
    float mm[4] = { m4.x, m4.y, m4.z, m4.w };
    float gg[4] = { dg4.x, dg4.y, dg4.z, dg4.w };
    float pp[4] = { dp4.x, dp4.y, dp4.z, dp4.w };
    float acc = 0;
#pragma unroll
    for (int k = 0; k < 4; ++k) {
        float m  = mm[k] > 0.5f ? 1.0f : 0.0f;
        float vg = (m == 1.0f) ? nan0(gg[k]) : 0.0f;
        float vp = (m == 1.0f) ? nan0(pp[k]) : 0.0f;
        acc += fabsf(vg * scale - vp);
    }
    float tot = blockReduce(acc, sbuf);
    if (threadIdx.x == 0) atomicAdd(&ws[SLOT(9, blockIdx.x)], tot);
}

// ---------------------------------------------------------------------------
// single-block finalize: sum the 8 slots of each quantity, reduce chamfer
// min array, assemble the loss.
__global__ __launch_bounds__(256) void k_finalize(
    const float* __restrict__ ws, const unsigned int* __restrict__ minarr,
    float* __restrict__ out)
{
    __shared__ float sbuf[4];
    __shared__ float q[NQ];
    int t = threadIdx.x;
    if (t < NQ) {
        float a = 0;
#pragma unroll
        for (int s = 0; s < 8; ++s) a += ws[t*QSTRIDE + s*16];
        q[t] = a;
    }
    float pcacc = 0;
#pragma unroll 4
    for (int i = t; i < 2 * SPTS; i += 256) {
        float v = __uint_as_float(minarr[i]);    // d2/2
        pcacc += sqrtf(fmaxf(2.0f * v, 0.0f));
    }
    float pcsum = blockReduce(pcacc, sbuf);
    __syncthreads();
    if (t == 0) {
        float mask_sum = q[0] + 1e-5f;
        float normal_loss = q[1] / mask_sum;
        float depth_loss = q[9] / (mask_sum + 1e-8f);
        if (q[2] < 1e-10f) depth_loss = 0.0f;
        depth_loss = nan0(depth_loss);
        float pc_loss  = pcsum / (float)SPTS;    // both dirs share the /8192
        float bce      = q[4] / (float)NPIX;
        float eik      = q[5] / (float)NEIK;
        float sdf_loss = q[6] / (float)NSDF;
        float con      = q[8] > 0.0f ? q[7] / q[8] : 0.0f;
        out[0] = normal_loss + depth_loss + pc_loss + bce + eik + sdf_loss + con;
    }
}

// ---------------------------------------------------------------------------
extern "C" void kernel_launch(void* const* d_in, const int* in_sizes, int n_in,
                              void* d_out, int out_size, void* d_ws, size_t ws_size,
                              hipStream_t stream) {
    const float* normal_pred = (const float*)d_in[0];
    const float* normal_gt   = (const float*)d_in[1];
    const float* depth_pred  = (const float*)d_in[2];
    const float* depth_gt    = (const float*)d_in[3];
    const float* X           = (const float*)d_in[4];
    const float* Y           = (const float*)d_in[5];
    const float* mask        = (const float*)d_in[6];
    const float* comp_mask   = (const float*)d_in[7];
    const float* gradients   = (const float*)d_in[8];
    const float* sdf         = (const float*)d_in[9];
    const float* nwa         = (const float*)d_in[10];
    const float* vm          = (const float*)d_in[11];
    const float* wts         = (const float*)d_in[12];
    float*        ws  = (float*)d_ws;
    unsigned int* wsu = (unsigned int*)d_ws;
    unsigned int* minarr = wsu + OFF_MIN;
    float* out = (float*)d_out;

    k_init<<<dim3(WS_WORDS / 256), dim3(256), 0, stream>>>(wsu);   // 69 blocks
    k_sums<<<dim3(B_SUMS), dim3(256), 0, stream>>>(
        normal_pred, normal_gt, depth_pred, depth_gt, mask, comp_mask,
        gradients, sdf, nwa, vm, wts, ws);
    k_chamfer<<<dim3(512), dim3(256), 0, stream>>>(X, Y, minarr);
    k_depth<<<dim3(B_DEP), dim3(256), 0, stream>>>(depth_pred, depth_gt, mask, ws);
    k_finalize<<<dim3(1), dim3(256), 0, stream>>>(ws, minarr, out);
}